// Round 9
// baseline (230.365 us; speedup 1.0000x reference)
//
#include <hip/hip_runtime.h>
#include <math.h>

#define N_NODES 20000
#define N_EDGES 320000
#define NFEAT 512
#define NHID 256
#define NCLASS 64

typedef __attribute__((ext_vector_type(8))) short bf16x8;
typedef __attribute__((ext_vector_type(4))) float f32x4;

__device__ __forceinline__ float selu_f(float x) {
    const float alpha = 1.6732632423543772f;
    const float scale = 1.0507009873554805f;
    return x > 0.f ? scale * x : scale * alpha * (expf(x) - 1.f);
}

__device__ __forceinline__ short f2bf(float f) {
    unsigned u = __builtin_bit_cast(unsigned, f);
    unsigned r = (u + 0x7FFFu + ((u >> 16) & 1u)) >> 16;   // RNE
    return (short)r;
}

__device__ __forceinline__ float bf2f(unsigned short b) {
    unsigned u = ((unsigned)b) << 16;
    return __builtin_bit_cast(float, u);
}

// ---------- fused: edge-count atomics + weight transpose-casts (disjoint ranges) ----------
__global__ void k_count_cast(const int* __restrict__ row, int* __restrict__ counts,
                             const float* __restrict__ W1, const float* __restrict__ W2,
                             short* __restrict__ w1t, short* __restrict__ w2t) {
    int t = blockIdx.x * blockDim.x + threadIdx.x;
    if (t < N_EDGES) {
        atomicAdd(&counts[row[t]], 1);
        return;
    }
    int u = t - N_EDGES;
    if (u < NFEAT * NHID) {
        int n = u / NFEAT, k = u % NFEAT;
        w1t[u] = f2bf(W1[(size_t)k * NHID + n]);
        return;
    }
    int v = u - NFEAT * NHID;
    if (v < NHID * NCLASS) {
        int n = v / NHID, k = v % NHID;
        w2t[v] = f2bf(W2[(size_t)k * NCLASS + n]);
    }
}

// single-pass scan: 1024 threads x 20 contiguous elems each, 2 barriers total
__global__ __launch_bounds__(1024) void k_scan(const int* __restrict__ counts,
                                               int* __restrict__ row_ptr,
                                               int* __restrict__ write_ptr) {
    __shared__ int wsum[16];
    int tid = threadIdx.x, lane = tid & 63, wave = tid >> 6;
    int base = tid * 20;
    int v[20];
    int s = 0;
    #pragma unroll
    for (int j = 0; j < 20; ++j) {
        int i = base + j;
        int c = (i < N_NODES) ? counts[i] : 0;
        v[j] = s;                 // exclusive prefix within thread
        s += c;
    }
    int ws = s;                    // inclusive wave scan of thread totals
    #pragma unroll
    for (int d = 1; d < 64; d <<= 1) {
        int t = __shfl_up(ws, d);
        if (lane >= d) ws += t;
    }
    if (lane == 63) wsum[wave] = ws;
    __syncthreads();
    if (wave == 0) {
        int t = (lane < 16) ? wsum[lane] : 0;
        #pragma unroll
        for (int d = 1; d < 16; d <<= 1) {
            int u = __shfl_up(t, d);
            if (lane >= d) t += u;
        }
        if (lane < 16) wsum[lane] = t;   // inclusive over waves
    }
    __syncthreads();
    int off = (wave ? wsum[wave - 1] : 0) + (ws - s);
    #pragma unroll
    for (int j = 0; j < 20; ++j) {
        int i = base + j;
        if (i < N_NODES) { row_ptr[i] = off + v[j]; write_ptr[i] = off + v[j]; }
    }
    if (tid == 0) row_ptr[N_NODES] = wsum[15];
}

// pack (col, weight) per edge -> one 8B load on the gather chain
__global__ void k_scatter(const int* __restrict__ row, const int* __restrict__ col,
                          const float* __restrict__ w, int* __restrict__ write_ptr,
                          int2* __restrict__ epack) {
    int e = blockIdx.x * blockDim.x + threadIdx.x;
    if (e < N_EDGES) {
        int r = row[e];
        int pos = atomicAdd(&write_ptr[r], 1);
        epack[pos] = make_int2(col[e], __builtin_bit_cast(int, w[e]));
    }
}

// ---------- bf16 MFMA GEMM: C[M,N] = A[M,K] @ Bt[N,K]^T; A fp32 (cast fused) or bf16 ----------
template<int BM, int BN, int BK, int MREP, int NREP, bool AFP32>
__global__ __launch_bounds__(256) void k_gemm_bf16(
    const void* __restrict__ Av, const short* __restrict__ Bt,
    short* __restrict__ C, int M, int N, int K)
{
    constexpr int LDT = BK + 8;   // +16B pad: frag reads 2-way bank alias (free, m136)
    __shared__ short As[BM * LDT];
    __shared__ short Bs[BN * LDT];
    const int tid = threadIdx.x;
    const int lane = tid & 63;
    const int w = tid >> 6;
    const int wr = w >> 1, wc = w & 1;
    const int m0 = blockIdx.x * BM, n0 = blockIdx.y * BN;
    constexpr int SEGS = BK / 8;
    constexpr int A_ITER = BM * SEGS / 256;
    constexpr int B_ITER = BN * SEGS / 256;

    f32x4 acc[MREP][NREP] = {};

    for (int kt = 0; kt < K; kt += BK) {
        #pragma unroll
        for (int it = 0; it < A_ITER; ++it) {
            int idx = tid + it * 256;
            int r = idx / SEGS, seg = idx % SEGS;
            int gr = m0 + r; if (gr >= M) gr = M - 1;   // clamp: dup load, store predicated
            bf16x8 o;
            if constexpr (AFP32) {
                const float* ap = (const float*)Av + (size_t)gr * K + kt + seg * 8;
                float4 p0 = *(const float4*)ap, p1 = *(const float4*)(ap + 4);
                o[0] = f2bf(p0.x); o[1] = f2bf(p0.y); o[2] = f2bf(p0.z); o[3] = f2bf(p0.w);
                o[4] = f2bf(p1.x); o[5] = f2bf(p1.y); o[6] = f2bf(p1.z); o[7] = f2bf(p1.w);
            } else {
                o = *(const bf16x8*)((const short*)Av + (size_t)gr * K + kt + seg * 8);
            }
            *(bf16x8*)(As + r * LDT + seg * 8) = o;
        }
        #pragma unroll
        for (int it = 0; it < B_ITER; ++it) {
            int idx = tid + it * 256;
            int r = idx / SEGS, seg = idx % SEGS;
            *(bf16x8*)(Bs + r * LDT + seg * 8) =
                *(const bf16x8*)(Bt + (size_t)(n0 + r) * K + kt + seg * 8);
        }
        __syncthreads();
        #pragma unroll
        for (int ks = 0; ks < BK / 32; ++ks) {
            bf16x8 a[MREP], b[NREP];
            #pragma unroll
            for (int m = 0; m < MREP; ++m)
                a[m] = *(const bf16x8*)(As + (wr * (BM / 2) + m * 16 + (lane & 15)) * LDT
                                        + ks * 32 + (lane >> 4) * 8);
            #pragma unroll
            for (int n = 0; n < NREP; ++n)
                b[n] = *(const bf16x8*)(Bs + (wc * (BN / 2) + n * 16 + (lane & 15)) * LDT
                                        + ks * 32 + (lane >> 4) * 8);
            #pragma unroll
            for (int m = 0; m < MREP; ++m)
                #pragma unroll
                for (int n = 0; n < NREP; ++n)
                    acc[m][n] = __builtin_amdgcn_mfma_f32_16x16x32_bf16(a[m], b[n], acc[m][n], 0, 0, 0);
        }
        __syncthreads();
    }
    // C/D layout (m89): col = lane&15, row = (lane>>4)*4 + reg
    #pragma unroll
    for (int m = 0; m < MREP; ++m) {
        #pragma unroll
        for (int n = 0; n < NREP; ++n) {
            #pragma unroll
            for (int r = 0; r < 4; ++r) {
                int grow = m0 + wr * (BM / 2) + m * 16 + (lane >> 4) * 4 + r;
                int gcol = n0 + wc * (BN / 2) + n * 16 + (lane & 15);
                if (grow < M) C[(size_t)grow * N + gcol] = f2bf(acc[m][n][r]);
            }
        }
    }
}

// ---------- layer-1 aggregation: 1 wave/node, ILP-4 edge unroll ----------
__global__ __launch_bounds__(256) void k_agg1(const short* __restrict__ support,
                                              const int* __restrict__ row_ptr,
                                              const int2* __restrict__ epack,
                                              const float* __restrict__ b1,
                                              short* __restrict__ h1) {
    int wid = (blockIdx.x * 256 + threadIdx.x) >> 6;   // = node
    int lane = threadIdx.x & 63;
    if (wid >= N_NODES) return;
    int e0 = row_ptr[wid], e1 = row_ptr[wid + 1];
    float a0[4] = {}, a1[4] = {}, a2[4] = {}, a3[4] = {};
    int e = e0;
    for (; e + 4 <= e1; e += 4) {
        int2 m0 = epack[e + 0], m1 = epack[e + 1], m2 = epack[e + 2], m3 = epack[e + 3];
        ushort4 v0 = *(const ushort4*)(support + (size_t)m0.x * NHID + lane * 4);
        ushort4 v1 = *(const ushort4*)(support + (size_t)m1.x * NHID + lane * 4);
        ushort4 v2 = *(const ushort4*)(support + (size_t)m2.x * NHID + lane * 4);
        ushort4 v3 = *(const ushort4*)(support + (size_t)m3.x * NHID + lane * 4);
        float w0 = __builtin_bit_cast(float, m0.y), w1 = __builtin_bit_cast(float, m1.y);
        float w2 = __builtin_bit_cast(float, m2.y), w3 = __builtin_bit_cast(float, m3.y);
        a0[0] = fmaf(w0, bf2f(v0.x), a0[0]); a0[1] = fmaf(w0, bf2f(v0.y), a0[1]);
        a0[2] = fmaf(w0, bf2f(v0.z), a0[2]); a0[3] = fmaf(w0, bf2f(v0.w), a0[3]);
        a1[0] = fmaf(w1, bf2f(v1.x), a1[0]); a1[1] = fmaf(w1, bf2f(v1.y), a1[1]);
        a1[2] = fmaf(w1, bf2f(v1.z), a1[2]); a1[3] = fmaf(w1, bf2f(v1.w), a1[3]);
        a2[0] = fmaf(w2, bf2f(v2.x), a2[0]); a2[1] = fmaf(w2, bf2f(v2.y), a2[1]);
        a2[2] = fmaf(w2, bf2f(v2.z), a2[2]); a2[3] = fmaf(w2, bf2f(v2.w), a2[3]);
        a3[0] = fmaf(w3, bf2f(v3.x), a3[0]); a3[1] = fmaf(w3, bf2f(v3.y), a3[1]);
        a3[2] = fmaf(w3, bf2f(v3.z), a3[2]); a3[3] = fmaf(w3, bf2f(v3.w), a3[3]);
    }
    for (; e < e1; ++e) {
        int2 m = epack[e];
        float wgt = __builtin_bit_cast(float, m.y);
        ushort4 v = *(const ushort4*)(support + (size_t)m.x * NHID + lane * 4);
        a0[0] = fmaf(wgt, bf2f(v.x), a0[0]); a0[1] = fmaf(wgt, bf2f(v.y), a0[1]);
        a0[2] = fmaf(wgt, bf2f(v.z), a0[2]); a0[3] = fmaf(wgt, bf2f(v.w), a0[3]);
    }
    ushort4 o;
    o.x = (unsigned short)f2bf(selu_f(a0[0] + a1[0] + a2[0] + a3[0] + b1[lane * 4 + 0]));
    o.y = (unsigned short)f2bf(selu_f(a0[1] + a1[1] + a2[1] + a3[1] + b1[lane * 4 + 1]));
    o.z = (unsigned short)f2bf(selu_f(a0[2] + a1[2] + a2[2] + a3[2] + b1[lane * 4 + 2]));
    o.w = (unsigned short)f2bf(selu_f(a0[3] + a1[3] + a2[3] + a3[3] + b1[lane * 4 + 3]));
    *(ushort4*)(h1 + (size_t)wid * NHID + lane * 4) = o;
}

// ---------- layer-2 aggregation: 2 nodes/wave, ILP-4, block-level partials ----------
#define AGG2_BLOCKS (N_NODES / 8)    // 2500 blocks, 8 nodes/block
__global__ __launch_bounds__(256) void k_agg2(const short* __restrict__ support2,
                                              const int* __restrict__ row_ptr,
                                              const int2* __restrict__ epack,
                                              const float* __restrict__ b2,
                                              float* __restrict__ partial) {
    __shared__ float bsum[4][64];
    int tid = threadIdx.x, lane = tid & 63, wave = tid >> 6;
    float bias = b2[lane];
    float local = 0.f;
    #pragma unroll
    for (int q = 0; q < 2; ++q) {
        int node = blockIdx.x * 8 + wave * 2 + q;
        int e0 = row_ptr[node], e1 = row_ptr[node + 1];
        float s0 = 0.f, s1 = 0.f, s2 = 0.f, s3 = 0.f;
        int e = e0;
        for (; e + 4 <= e1; e += 4) {
            int2 m0 = epack[e + 0], m1 = epack[e + 1], m2 = epack[e + 2], m3 = epack[e + 3];
            float v0 = bf2f((unsigned short)support2[(size_t)m0.x * NCLASS + lane]);
            float v1 = bf2f((unsigned short)support2[(size_t)m1.x * NCLASS + lane]);
            float v2 = bf2f((unsigned short)support2[(size_t)m2.x * NCLASS + lane]);
            float v3 = bf2f((unsigned short)support2[(size_t)m3.x * NCLASS + lane]);
            s0 = fmaf(__builtin_bit_cast(float, m0.y), v0, s0);
            s1 = fmaf(__builtin_bit_cast(float, m1.y), v1, s1);
            s2 = fmaf(__builtin_bit_cast(float, m2.y), v2, s2);
            s3 = fmaf(__builtin_bit_cast(float, m3.y), v3, s3);
        }
        for (; e < e1; ++e) {
            int2 m = epack[e];
            s0 = fmaf(__builtin_bit_cast(float, m.y),
                      bf2f((unsigned short)support2[(size_t)m.x * NCLASS + lane]), s0);
        }
        local += selu_f(s0 + s1 + s2 + s3 + bias);
    }
    bsum[wave][lane] = local;
    __syncthreads();
    if (tid < 64)
        partial[(size_t)blockIdx.x * 64 + tid] =
            bsum[0][tid] + bsum[1][tid] + bsum[2][tid] + bsum[3][tid];
}

// ---------- reduce stage 1: 50 blocks x 50 rows -> stage2[50][64] ----------
#define RED_BLOCKS 50
#define RED_ROWS (AGG2_BLOCKS / RED_BLOCKS)   // 50
__global__ __launch_bounds__(256) void k_reduce1(const float* __restrict__ partial,
                                                 float* __restrict__ stage2) {
    __shared__ float red[4][64];
    int tid = threadIdx.x, lane = tid & 63, sl = tid >> 6;
    int r0 = blockIdx.x * RED_ROWS;
    float s = 0.f;
    for (int i = sl; i < RED_ROWS; i += 4)        // coalesced 256B rows, indep loads
        s += partial[(size_t)(r0 + i) * 64 + lane];
    red[sl][lane] = s;
    __syncthreads();
    if (tid < 64)
        stage2[(size_t)blockIdx.x * 64 + tid] =
            red[0][tid] + red[1][tid] + red[2][tid] + red[3][tid];
}

// ---------- final: sum 50 stage2 rows -> mean -> selu -> log_softmax (1 wave) ----------
__global__ void k_final(const float* __restrict__ stage2, float* __restrict__ out) {
    int lane = threadIdx.x;   // 64 threads
    float tot = 0.f;
    #pragma unroll
    for (int i = 0; i < RED_BLOCKS; ++i)          // independent loads, one latency
        tot += stage2[(size_t)i * 64 + lane];
    float v = selu_f(tot * (1.0f / N_NODES));
    float m = v;
    #pragma unroll
    for (int off = 32; off >= 1; off >>= 1) m = fmaxf(m, __shfl_xor(m, off));
    float ex = expf(v - m);
    float ssum = ex;
    #pragma unroll
    for (int off = 32; off >= 1; off >>= 1) ssum += __shfl_xor(ssum, off);
    out[lane] = v - m - logf(ssum);
}

extern "C" void kernel_launch(void* const* d_in, const int* in_sizes, int n_in,
                              void* d_out, int out_size, void* d_ws, size_t ws_size,
                              hipStream_t stream) {
    const float* x  = (const float*)d_in[0];
    const int* ei   = (const int*)d_in[1];
    const float* ew = (const float*)d_in[2];
    const float* W1 = (const float*)d_in[3];
    const float* b1 = (const float*)d_in[4];
    const float* W2 = (const float*)d_in[5];
    const float* b2 = (const float*)d_in[6];
    float* out = (float*)d_out;
    const int* e_row = ei;
    const int* e_col = ei + N_EDGES;

    char* p = (char*)d_ws;
    short* w1t      = (short*)p;  p += (size_t)NHID * NFEAT * 2;        //  0.26 MB
    short* w2t      = (short*)p;  p += (size_t)NCLASS * NHID * 2;       //  0.03 MB
    short* support1 = (short*)p;  p += (size_t)N_NODES * NHID * 2;      // 10.24 MB
    short* h1       = (short*)p;  p += (size_t)N_NODES * NHID * 2;      // 10.24 MB
    int* counts     = (int*)p;    p += (size_t)N_NODES * 4;
    int* row_ptr    = (int*)p;    p += (size_t)(N_NODES + 1) * 4;
    int* write_ptr  = (int*)p;    p += (size_t)N_NODES * 4;
    int2* epack     = (int2*)p;   p += (size_t)N_EDGES * 8;             //  2.56 MB
    float* partial  = (float*)p;  p += (size_t)AGG2_BLOCKS * 64 * 4;    //  0.64 MB
    float* stage2   = (float*)p;  p += (size_t)RED_BLOCKS * 64 * 4;     //  0.01 MB
    short* support2 = support1;   // support1 dead after agg1

    hipMemsetAsync(counts, 0, (size_t)N_NODES * 4, stream);

    // CSR count + weight casts fused (disjoint blockIdx ranges)
    int fused_threads = N_EDGES + NFEAT * NHID + NHID * NCLASS;
    k_count_cast<<<(fused_threads + 255) / 256, 256, 0, stream>>>(
        e_row, counts, W1, W2, w1t, w2t);
    k_scan<<<1, 1024, 0, stream>>>(counts, row_ptr, write_ptr);
    k_scatter<<<(N_EDGES + 255) / 256, 256, 0, stream>>>(e_row, e_col, ew, write_ptr, epack);

    // layer 1 (x read as fp32, cast fused into staging); 64x128 tile: 626 blocks
    k_gemm_bf16<64, 128, 64, 2, 4, true>
        <<<dim3((N_NODES + 63) / 64, NHID / 128), 256, 0, stream>>>(
            x, w1t, support1, N_NODES, NHID, NFEAT);
    k_agg1<<<(N_NODES * 64 + 255) / 256, 256, 0, stream>>>(support1, row_ptr, epack, b1, h1);

    // layer 2
    k_gemm_bf16<64, 64, 32, 2, 2, false>
        <<<dim3((N_NODES + 63) / 64, NCLASS / 64), 256, 0, stream>>>(
            h1, w2t, support2, N_NODES, NCLASS, NHID);
    k_agg2<<<AGG2_BLOCKS, 256, 0, stream>>>(support2, row_ptr, epack, b2, partial);
    k_reduce1<<<RED_BLOCKS, 256, 0, stream>>>(partial, stage2);
    k_final<<<1, 64, 0, stream>>>(stage2, out);
}

// Round 12
// 225.342 us; speedup vs baseline: 1.0223x; 1.0223x over previous
//
#include <hip/hip_runtime.h>
#include <math.h>

#define N_NODES 20000
#define N_EDGES 320000
#define NFEAT 512
#define NHID 256
#define NCLASS 64

typedef __attribute__((ext_vector_type(8))) short bf16x8;
typedef __attribute__((ext_vector_type(4))) float f32x4;

__device__ __forceinline__ float selu_f(float x) {
    const float alpha = 1.6732632423543772f;
    const float scale = 1.0507009873554805f;
    return x > 0.f ? scale * x : scale * alpha * (expf(x) - 1.f);
}

__device__ __forceinline__ short f2bf(float f) {
    unsigned u = __builtin_bit_cast(unsigned, f);
    unsigned r = (u + 0x7FFFu + ((u >> 16) & 1u)) >> 16;   // RNE
    return (short)r;
}

__device__ __forceinline__ float bf2f(unsigned short b) {
    unsigned u = ((unsigned)b) << 16;
    return __builtin_bit_cast(float, u);
}

// ---------- fused: edge-count atomics + coalesced 32x32 LDS-tiled weight transpose ----------
#define EDGE_BLOCKS ((N_EDGES + 255) / 256)          // 1250
#define W1_TILES ((NFEAT / 32) * (NHID / 32))        // 16 x 8 = 128
#define W2_TILES ((NHID / 32) * (NCLASS / 32))       // 8 x 2 = 16
__global__ __launch_bounds__(256) void k_count_cast(
    const int* __restrict__ row, int* __restrict__ counts,
    const float* __restrict__ W1, const float* __restrict__ W2,
    short* __restrict__ w1t, short* __restrict__ w2t)
{
    __shared__ float tile[32][33];
    int b = blockIdx.x, tid = threadIdx.x;
    if (b < EDGE_BLOCKS) {
        int e = b * 256 + tid;
        if (e < N_EDGES) atomicAdd(&counts[row[e]], 1);
        return;
    }
    int t = b - EDGE_BLOCKS;
    const float* W; short* Wt; int K, N, tk, tn;
    if (t < W1_TILES) { W = W1; Wt = w1t; K = NFEAT; N = NHID; tk = t & 15; tn = t >> 4; }
    else { t -= W1_TILES; W = W2; Wt = w2t; K = NHID; N = NCLASS; tk = t & 7; tn = t >> 3; }
    int c = tid & 31, r0 = tid >> 5;                 // 8 rows per pass
    int k0 = tk * 32, n0 = tn * 32;
    #pragma unroll
    for (int i = 0; i < 4; ++i) {
        int r = r0 + i * 8;
        tile[r][c] = W[(size_t)(k0 + r) * N + n0 + c];   // coalesced read
    }
    __syncthreads();
    #pragma unroll
    for (int i = 0; i < 4; ++i) {
        int r = r0 + i * 8;
        Wt[(size_t)(n0 + r) * K + k0 + c] = f2bf(tile[c][r]);  // coalesced write
    }
}

// single-pass scan: 1024 threads x 20 contiguous elems each, 2 barriers total
__global__ __launch_bounds__(1024) void k_scan(const int* __restrict__ counts,
                                               int* __restrict__ row_ptr,
                                               int* __restrict__ write_ptr) {
    __shared__ int wsum[16];
    int tid = threadIdx.x, lane = tid & 63, wave = tid >> 6;
    int base = tid * 20;
    int v[20];
    int s = 0;
    #pragma unroll
    for (int j = 0; j < 20; ++j) {
        int i = base + j;
        int c = (i < N_NODES) ? counts[i] : 0;
        v[j] = s;                 // exclusive prefix within thread
        s += c;
    }
    int ws = s;                    // inclusive wave scan of thread totals
    #pragma unroll
    for (int d = 1; d < 64; d <<= 1) {
        int t = __shfl_up(ws, d);
        if (lane >= d) ws += t;
    }
    if (lane == 63) wsum[wave] = ws;
    __syncthreads();
    if (wave == 0) {
        int t = (lane < 16) ? wsum[lane] : 0;
        #pragma unroll
        for (int d = 1; d < 16; d <<= 1) {
            int u = __shfl_up(t, d);
            if (lane >= d) t += u;
        }
        if (lane < 16) wsum[lane] = t;   // inclusive over waves
    }
    __syncthreads();
    int off = (wave ? wsum[wave - 1] : 0) + (ws - s);
    #pragma unroll
    for (int j = 0; j < 20; ++j) {
        int i = base + j;
        if (i < N_NODES) { row_ptr[i] = off + v[j]; write_ptr[i] = off + v[j]; }
    }
    if (tid == 0) row_ptr[N_NODES] = wsum[15];
}

// pack (col, weight) per edge -> one 8B load on the gather chain
__global__ void k_scatter(const int* __restrict__ row, const int* __restrict__ col,
                          const float* __restrict__ w, int* __restrict__ write_ptr,
                          int2* __restrict__ epack) {
    int e = blockIdx.x * blockDim.x + threadIdx.x;
    if (e < N_EDGES) {
        int r = row[e];
        int pos = atomicAdd(&write_ptr[r], 1);
        epack[pos] = make_int2(col[e], __builtin_bit_cast(int, w[e]));
    }
}

// ---------- bf16 MFMA GEMM: C[M,N] = A[M,K] @ Bt[N,K]^T; A fp32 (cast fused) or bf16 ----------
template<int BM, int BN, int BK, int MREP, int NREP, bool AFP32>
__global__ __launch_bounds__(256) void k_gemm_bf16(
    const void* __restrict__ Av, const short* __restrict__ Bt,
    short* __restrict__ C, int M, int N, int K)
{
    constexpr int LDT = BK + 8;   // +16B pad: frag reads 2-way bank alias (free, m136)
    __shared__ short As[BM * LDT];
    __shared__ short Bs[BN * LDT];
    const int tid = threadIdx.x;
    const int lane = tid & 63;
    const int w = tid >> 6;
    const int wr = w >> 1, wc = w & 1;
    const int m0 = blockIdx.x * BM, n0 = blockIdx.y * BN;
    constexpr int SEGS = BK / 8;
    constexpr int A_ITER = BM * SEGS / 256;
    constexpr int B_ITER = BN * SEGS / 256;

    f32x4 acc[MREP][NREP] = {};

    for (int kt = 0; kt < K; kt += BK) {
        #pragma unroll
        for (int it = 0; it < A_ITER; ++it) {
            int idx = tid + it * 256;
            int r = idx / SEGS, seg = idx % SEGS;
            int gr = m0 + r; if (gr >= M) gr = M - 1;   // clamp: dup load, store predicated
            bf16x8 o;
            if constexpr (AFP32) {
                const float* ap = (const float*)Av + (size_t)gr * K + kt + seg * 8;
                float4 p0 = *(const float4*)ap, p1 = *(const float4*)(ap + 4);
                o[0] = f2bf(p0.x); o[1] = f2bf(p0.y); o[2] = f2bf(p0.z); o[3] = f2bf(p0.w);
                o[4] = f2bf(p1.x); o[5] = f2bf(p1.y); o[6] = f2bf(p1.z); o[7] = f2bf(p1.w);
            } else {
                o = *(const bf16x8*)((const short*)Av + (size_t)gr * K + kt + seg * 8);
            }
            *(bf16x8*)(As + r * LDT + seg * 8) = o;
        }
        #pragma unroll
        for (int it = 0; it < B_ITER; ++it) {
            int idx = tid + it * 256;
            int r = idx / SEGS, seg = idx % SEGS;
            *(bf16x8*)(Bs + r * LDT + seg * 8) =
                *(const bf16x8*)(Bt + (size_t)(n0 + r) * K + kt + seg * 8);
        }
        __syncthreads();
        #pragma unroll
        for (int ks = 0; ks < BK / 32; ++ks) {
            bf16x8 a[MREP], b[NREP];
            #pragma unroll
            for (int m = 0; m < MREP; ++m)
                a[m] = *(const bf16x8*)(As + (wr * (BM / 2) + m * 16 + (lane & 15)) * LDT
                                        + ks * 32 + (lane >> 4) * 8);
            #pragma unroll
            for (int n = 0; n < NREP; ++n)
                b[n] = *(const bf16x8*)(Bs + (wc * (BN / 2) + n * 16 + (lane & 15)) * LDT
                                        + ks * 32 + (lane >> 4) * 8);
            #pragma unroll
            for (int m = 0; m < MREP; ++m)
                #pragma unroll
                for (int n = 0; n < NREP; ++n)
                    acc[m][n] = __builtin_amdgcn_mfma_f32_16x16x32_bf16(a[m], b[n], acc[m][n], 0, 0, 0);
        }
        __syncthreads();
    }
    // C/D layout (m89): col = lane&15, row = (lane>>4)*4 + reg
    #pragma unroll
    for (int m = 0; m < MREP; ++m) {
        #pragma unroll
        for (int n = 0; n < NREP; ++n) {
            #pragma unroll
            for (int r = 0; r < 4; ++r) {
                int grow = m0 + wr * (BM / 2) + m * 16 + (lane >> 4) * 4 + r;
                int gcol = n0 + wc * (BN / 2) + n * 16 + (lane & 15);
                if (grow < M) C[(size_t)grow * N + gcol] = f2bf(acc[m][n][r]);
            }
        }
    }
}

// ---------- layer-1 aggregation: 1 wave/node, ILP-4 edge unroll ----------
__global__ __launch_bounds__(256) void k_agg1(const short* __restrict__ support,
                                              const int* __restrict__ row_ptr,
                                              const int2* __restrict__ epack,
                                              const float* __restrict__ b1,
                                              short* __restrict__ h1) {
    int wid = (blockIdx.x * 256 + threadIdx.x) >> 6;   // = node
    int lane = threadIdx.x & 63;
    if (wid >= N_NODES) return;
    int e0 = row_ptr[wid], e1 = row_ptr[wid + 1];
    float a0[4] = {}, a1[4] = {}, a2[4] = {}, a3[4] = {};
    int e = e0;
    for (; e + 4 <= e1; e += 4) {
        int2 m0 = epack[e + 0], m1 = epack[e + 1], m2 = epack[e + 2], m3 = epack[e + 3];
        ushort4 v0 = *(const ushort4*)(support + (size_t)m0.x * NHID + lane * 4);
        ushort4 v1 = *(const ushort4*)(support + (size_t)m1.x * NHID + lane * 4);
        ushort4 v2 = *(const ushort4*)(support + (size_t)m2.x * NHID + lane * 4);
        ushort4 v3 = *(const ushort4*)(support + (size_t)m3.x * NHID + lane * 4);
        float w0 = __builtin_bit_cast(float, m0.y), w1 = __builtin_bit_cast(float, m1.y);
        float w2 = __builtin_bit_cast(float, m2.y), w3 = __builtin_bit_cast(float, m3.y);
        a0[0] = fmaf(w0, bf2f(v0.x), a0[0]); a0[1] = fmaf(w0, bf2f(v0.y), a0[1]);
        a0[2] = fmaf(w0, bf2f(v0.z), a0[2]); a0[3] = fmaf(w0, bf2f(v0.w), a0[3]);
        a1[0] = fmaf(w1, bf2f(v1.x), a1[0]); a1[1] = fmaf(w1, bf2f(v1.y), a1[1]);
        a1[2] = fmaf(w1, bf2f(v1.z), a1[2]); a1[3] = fmaf(w1, bf2f(v1.w), a1[3]);
        a2[0] = fmaf(w2, bf2f(v2.x), a2[0]); a2[1] = fmaf(w2, bf2f(v2.y), a2[1]);
        a2[2] = fmaf(w2, bf2f(v2.z), a2[2]); a2[3] = fmaf(w2, bf2f(v2.w), a2[3]);
        a3[0] = fmaf(w3, bf2f(v3.x), a3[0]); a3[1] = fmaf(w3, bf2f(v3.y), a3[1]);
        a3[2] = fmaf(w3, bf2f(v3.z), a3[2]); a3[3] = fmaf(w3, bf2f(v3.w), a3[3]);
    }
    for (; e < e1; ++e) {
        int2 m = epack[e];
        float wgt = __builtin_bit_cast(float, m.y);
        ushort4 v = *(const ushort4*)(support + (size_t)m.x * NHID + lane * 4);
        a0[0] = fmaf(wgt, bf2f(v.x), a0[0]); a0[1] = fmaf(wgt, bf2f(v.y), a0[1]);
        a0[2] = fmaf(wgt, bf2f(v.z), a0[2]); a0[3] = fmaf(wgt, bf2f(v.w), a0[3]);
    }
    ushort4 o;
    o.x = (unsigned short)f2bf(selu_f(a0[0] + a1[0] + a2[0] + a3[0] + b1[lane * 4 + 0]));
    o.y = (unsigned short)f2bf(selu_f(a0[1] + a1[1] + a2[1] + a3[1] + b1[lane * 4 + 1]));
    o.z = (unsigned short)f2bf(selu_f(a0[2] + a1[2] + a2[2] + a3[2] + b1[lane * 4 + 2]));
    o.w = (unsigned short)f2bf(selu_f(a0[3] + a1[3] + a2[3] + a3[3] + b1[lane * 4 + 3]));
    *(ushort4*)(h1 + (size_t)wid * NHID + lane * 4) = o;
}

// ---------- layer-2 aggregation: 2 nodes/wave, ILP-4, block-level partials ----------
#define AGG2_BLOCKS (N_NODES / 8)    // 2500 blocks, 8 nodes/block
__global__ __launch_bounds__(256) void k_agg2(const short* __restrict__ support2,
                                              const int* __restrict__ row_ptr,
                                              const int2* __restrict__ epack,
                                              const float* __restrict__ b2,
                                              float* __restrict__ partial) {
    __shared__ float bsum[4][64];
    int tid = threadIdx.x, lane = tid & 63, wave = tid >> 6;
    float bias = b2[lane];
    float local = 0.f;
    #pragma unroll
    for (int q = 0; q < 2; ++q) {
        int node = blockIdx.x * 8 + wave * 2 + q;
        int e0 = row_ptr[node], e1 = row_ptr[node + 1];
        float s0 = 0.f, s1 = 0.f, s2 = 0.f, s3 = 0.f;
        int e = e0;
        for (; e + 4 <= e1; e += 4) {
            int2 m0 = epack[e + 0], m1 = epack[e + 1], m2 = epack[e + 2], m3 = epack[e + 3];
            float v0 = bf2f((unsigned short)support2[(size_t)m0.x * NCLASS + lane]);
            float v1 = bf2f((unsigned short)support2[(size_t)m1.x * NCLASS + lane]);
            float v2 = bf2f((unsigned short)support2[(size_t)m2.x * NCLASS + lane]);
            float v3 = bf2f((unsigned short)support2[(size_t)m3.x * NCLASS + lane]);
            s0 = fmaf(__builtin_bit_cast(float, m0.y), v0, s0);
            s1 = fmaf(__builtin_bit_cast(float, m1.y), v1, s1);
            s2 = fmaf(__builtin_bit_cast(float, m2.y), v2, s2);
            s3 = fmaf(__builtin_bit_cast(float, m3.y), v3, s3);
        }
        for (; e < e1; ++e) {
            int2 m = epack[e];
            s0 = fmaf(__builtin_bit_cast(float, m.y),
                      bf2f((unsigned short)support2[(size_t)m.x * NCLASS + lane]), s0);
        }
        local += selu_f(s0 + s1 + s2 + s3 + bias);
    }
    bsum[wave][lane] = local;
    __syncthreads();
    if (tid < 64)
        partial[(size_t)blockIdx.x * 64 + tid] =
            bsum[0][tid] + bsum[1][tid] + bsum[2][tid] + bsum[3][tid];
}

// ---------- reduce stage 1: 50 blocks x 50 rows -> stage2[50][64] ----------
#define RED_BLOCKS 50
#define RED_ROWS (AGG2_BLOCKS / RED_BLOCKS)   // 50
__global__ __launch_bounds__(256) void k_reduce1(const float* __restrict__ partial,
                                                 float* __restrict__ stage2) {
    __shared__ float red[4][64];
    int tid = threadIdx.x, lane = tid & 63, sl = tid >> 6;
    int r0 = blockIdx.x * RED_ROWS;
    float s = 0.f;
    for (int i = sl; i < RED_ROWS; i += 4)        // coalesced 256B rows, indep loads
        s += partial[(size_t)(r0 + i) * 64 + lane];
    red[sl][lane] = s;
    __syncthreads();
    if (tid < 64)
        stage2[(size_t)blockIdx.x * 64 + tid] =
            red[0][tid] + red[1][tid] + red[2][tid] + red[3][tid];
}

// ---------- final: sum 50 stage2 rows -> mean -> selu -> log_softmax (1 wave) ----------
__global__ void k_final(const float* __restrict__ stage2, float* __restrict__ out) {
    int lane = threadIdx.x;   // 64 threads
    float tot = 0.f;
    #pragma unroll
    for (int i = 0; i < RED_BLOCKS; ++i)          // independent loads, one latency
        tot += stage2[(size_t)i * 64 + lane];
    float v = selu_f(tot * (1.0f / N_NODES));
    float m = v;
    #pragma unroll
    for (int off = 32; off >= 1; off >>= 1) m = fmaxf(m, __shfl_xor(m, off));
    float ex = expf(v - m);
    float ssum = ex;
    #pragma unroll
    for (int off = 32; off >= 1; off >>= 1) ssum += __shfl_xor(ssum, off);
    out[lane] = v - m - logf(ssum);
}

extern "C" void kernel_launch(void* const* d_in, const int* in_sizes, int n_in,
                              void* d_out, int out_size, void* d_ws, size_t ws_size,
                              hipStream_t stream) {
    const float* x  = (const float*)d_in[0];
    const int* ei   = (const int*)d_in[1];
    const float* ew = (const float*)d_in[2];
    const float* W1 = (const float*)d_in[3];
    const float* b1 = (const float*)d_in[4];
    const float* W2 = (const float*)d_in[5];
    const float* b2 = (const float*)d_in[6];
    float* out = (float*)d_out;
    const int* e_row = ei;
    const int* e_col = ei + N_EDGES;

    char* p = (char*)d_ws;
    short* w1t      = (short*)p;  p += (size_t)NHID * NFEAT * 2;        //  0.26 MB
    short* w2t      = (short*)p;  p += (size_t)NCLASS * NHID * 2;       //  0.03 MB
    short* support1 = (short*)p;  p += (size_t)N_NODES * NHID * 2;      // 10.24 MB
    short* h1       = (short*)p;  p += (size_t)N_NODES * NHID * 2;      // 10.24 MB
    int* counts     = (int*)p;    p += (size_t)N_NODES * 4;
    int* row_ptr    = (int*)p;    p += (size_t)(N_NODES + 1) * 4;
    int* write_ptr  = (int*)p;    p += (size_t)N_NODES * 4;
    int2* epack     = (int2*)p;   p += (size_t)N_EDGES * 8;             //  2.56 MB
    float* partial  = (float*)p;  p += (size_t)AGG2_BLOCKS * 64 * 4;    //  0.64 MB
    float* stage2   = (float*)p;  p += (size_t)RED_BLOCKS * 64 * 4;     //  0.01 MB
    short* support2 = support1;   // support1 dead after agg1

    hipMemsetAsync(counts, 0, (size_t)N_NODES * 4, stream);

    // CSR count + coalesced weight transpose-casts (disjoint block ranges)
    k_count_cast<<<EDGE_BLOCKS + W1_TILES + W2_TILES, 256, 0, stream>>>(
        e_row, counts, W1, W2, w1t, w2t);
    k_scan<<<1, 1024, 0, stream>>>(counts, row_ptr, write_ptr);
    k_scatter<<<(N_EDGES + 255) / 256, 256, 0, stream>>>(e_row, e_col, ew, write_ptr, epack);

    // layer 1: 64x256 tile, single column pass -> x fp32 read exactly once (82 MB)
    k_gemm_bf16<64, 256, 64, 2, 8, true>
        <<<dim3((N_NODES + 63) / 64, NHID / 256), 256, 0, stream>>>(
            x, w1t, support1, N_NODES, NHID, NFEAT);
    k_agg1<<<(N_NODES * 64 + 255) / 256, 256, 0, stream>>>(support1, row_ptr, epack, b1, h1);

    // layer 2
    k_gemm_bf16<64, 64, 32, 2, 2, false>
        <<<dim3((N_NODES + 63) / 64, NCLASS / 64), 256, 0, stream>>>(
            h1, w2t, support2, N_NODES, NCLASS, NHID);
    k_agg2<<<AGG2_BLOCKS, 256, 0, stream>>>(support2, row_ptr, epack, b2, partial);
    k_reduce1<<<RED_BLOCKS, 256, 0, stream>>>(partial, stage2);
    k_final<<<1, 64, 0, stream>>>(stage2, out);
}

// Round 14
// 217.704 us; speedup vs baseline: 1.0582x; 1.0351x over previous
//
#include <hip/hip_runtime.h>
#include <math.h>

#define N_NODES 20000
#define N_EDGES 320000
#define NFEAT 512
#define NHID 256
#define NCLASS 64

typedef __attribute__((ext_vector_type(8))) short bf16x8;
typedef __attribute__((ext_vector_type(4))) float f32x4;

__device__ __forceinline__ float selu_f(float x) {
    const float alpha = 1.6732632423543772f;
    const float scale = 1.0507009873554805f;
    return x > 0.f ? scale * x : scale * alpha * (expf(x) - 1.f);
}

__device__ __forceinline__ short f2bf(float f) {
    unsigned u = __builtin_bit_cast(unsigned, f);
    unsigned r = (u + 0x7FFFu + ((u >> 16) & 1u)) >> 16;   // RNE
    return (short)r;
}

__device__ __forceinline__ float bf2f(unsigned short b) {
    unsigned u = ((unsigned)b) << 16;
    return __builtin_bit_cast(float, u);
}

// ---------- fused: edge-count atomics + coalesced 32x32 LDS-tiled weight transpose ----------
#define EDGE_BLOCKS ((N_EDGES + 255) / 256)          // 1250
#define W1_TILES ((NFEAT / 32) * (NHID / 32))        // 16 x 8 = 128
#define W2_TILES ((NHID / 32) * (NCLASS / 32))       // 8 x 2 = 16
__global__ __launch_bounds__(256) void k_count_cast(
    const int* __restrict__ row, int* __restrict__ counts,
    const float* __restrict__ W1, const float* __restrict__ W2,
    short* __restrict__ w1t, short* __restrict__ w2t)
{
    __shared__ float tile[32][33];
    int b = blockIdx.x, tid = threadIdx.x;
    if (b < EDGE_BLOCKS) {
        int e = b * 256 + tid;
        if (e < N_EDGES) atomicAdd(&counts[row[e]], 1);
        return;
    }
    int t = b - EDGE_BLOCKS;
    const float* W; short* Wt; int K, N, tk, tn;
    if (t < W1_TILES) { W = W1; Wt = w1t; K = NFEAT; N = NHID; tk = t & 15; tn = t >> 4; }
    else { t -= W1_TILES; W = W2; Wt = w2t; K = NHID; N = NCLASS; tk = t & 7; tn = t >> 3; }
    int c = tid & 31, r0 = tid >> 5;                 // 8 rows per pass
    int k0 = tk * 32, n0 = tn * 32;
    #pragma unroll
    for (int i = 0; i < 4; ++i) {
        int r = r0 + i * 8;
        tile[r][c] = W[(size_t)(k0 + r) * N + n0 + c];   // coalesced read
    }
    __syncthreads();
    #pragma unroll
    for (int i = 0; i < 4; ++i) {
        int r = r0 + i * 8;
        Wt[(size_t)(n0 + r) * K + k0 + c] = f2bf(tile[c][r]);  // coalesced write
    }
}

// single-pass scan: 1024 threads x 20 contiguous elems each, 2 barriers total
__global__ __launch_bounds__(1024) void k_scan(const int* __restrict__ counts,
                                               int* __restrict__ row_ptr,
                                               int* __restrict__ write_ptr) {
    __shared__ int wsum[16];
    int tid = threadIdx.x, lane = tid & 63, wave = tid >> 6;
    int base = tid * 20;
    int v[20];
    int s = 0;
    #pragma unroll
    for (int j = 0; j < 20; ++j) {
        int i = base + j;
        int c = (i < N_NODES) ? counts[i] : 0;
        v[j] = s;                 // exclusive prefix within thread
        s += c;
    }
    int ws = s;                    // inclusive wave scan of thread totals
    #pragma unroll
    for (int d = 1; d < 64; d <<= 1) {
        int t = __shfl_up(ws, d);
        if (lane >= d) ws += t;
    }
    if (lane == 63) wsum[wave] = ws;
    __syncthreads();
    if (wave == 0) {
        int t = (lane < 16) ? wsum[lane] : 0;
        #pragma unroll
        for (int d = 1; d < 16; d <<= 1) {
            int u = __shfl_up(t, d);
            if (lane >= d) t += u;
        }
        if (lane < 16) wsum[lane] = t;   // inclusive over waves
    }
    __syncthreads();
    int off = (wave ? wsum[wave - 1] : 0) + (ws - s);
    #pragma unroll
    for (int j = 0; j < 20; ++j) {
        int i = base + j;
        if (i < N_NODES) { row_ptr[i] = off + v[j]; write_ptr[i] = off + v[j]; }
    }
    if (tid == 0) row_ptr[N_NODES] = wsum[15];
}

// pack (col, weight) per edge -> one 8B load on the gather chain
__global__ void k_scatter(const int* __restrict__ row, const int* __restrict__ col,
                          const float* __restrict__ w, int* __restrict__ write_ptr,
                          int2* __restrict__ epack) {
    int e = blockIdx.x * blockDim.x + threadIdx.x;
    if (e < N_EDGES) {
        int r = row[e];
        int pos = atomicAdd(&write_ptr[r], 1);
        epack[pos] = make_int2(col[e], __builtin_bit_cast(int, w[e]));
    }
}

// ---------- bf16 MFMA GEMM: C[M,N] = A[M,K] @ Bt[N,K]^T; A fp32 (cast fused) or bf16 ----------
template<int BM, int BN, int BK, int MREP, int NREP, bool AFP32>
__global__ __launch_bounds__(256) void k_gemm_bf16(
    const void* __restrict__ Av, const short* __restrict__ Bt,
    short* __restrict__ C, int M, int N, int K)
{
    constexpr int LDT = BK + 8;   // +16B pad: frag reads 2-way bank alias (free, m136)
    __shared__ short As[BM * LDT];
    __shared__ short Bs[BN * LDT];
    const int tid = threadIdx.x;
    const int lane = tid & 63;
    const int w = tid >> 6;
    const int wr = w >> 1, wc = w & 1;
    const int m0 = blockIdx.x * BM, n0 = blockIdx.y * BN;
    constexpr int SEGS = BK / 8;
    constexpr int A_ITER = BM * SEGS / 256;
    constexpr int B_ITER = BN * SEGS / 256;

    f32x4 acc[MREP][NREP] = {};

    for (int kt = 0; kt < K; kt += BK) {
        #pragma unroll
        for (int it = 0; it < A_ITER; ++it) {
            int idx = tid + it * 256;
            int r = idx / SEGS, seg = idx % SEGS;
            int gr = m0 + r; if (gr >= M) gr = M - 1;   // clamp: dup load, store predicated
            bf16x8 o;
            if constexpr (AFP32) {
                const float* ap = (const float*)Av + (size_t)gr * K + kt + seg * 8;
                float4 p0 = *(const float4*)ap, p1 = *(const float4*)(ap + 4);
                o[0] = f2bf(p0.x); o[1] = f2bf(p0.y); o[2] = f2bf(p0.z); o[3] = f2bf(p0.w);
                o[4] = f2bf(p1.x); o[5] = f2bf(p1.y); o[6] = f2bf(p1.z); o[7] = f2bf(p1.w);
            } else {
                o = *(const bf16x8*)((const short*)Av + (size_t)gr * K + kt + seg * 8);
            }
            *(bf16x8*)(As + r * LDT + seg * 8) = o;
        }
        #pragma unroll
        for (int it = 0; it < B_ITER; ++it) {
            int idx = tid + it * 256;
            int r = idx / SEGS, seg = idx % SEGS;
            *(bf16x8*)(Bs + r * LDT + seg * 8) =
                *(const bf16x8*)(Bt + (size_t)(n0 + r) * K + kt + seg * 8);
        }
        __syncthreads();
        #pragma unroll
        for (int ks = 0; ks < BK / 32; ++ks) {
            bf16x8 a[MREP], b[NREP];
            #pragma unroll
            for (int m = 0; m < MREP; ++m)
                a[m] = *(const bf16x8*)(As + (wr * (BM / 2) + m * 16 + (lane & 15)) * LDT
                                        + ks * 32 + (lane >> 4) * 8);
            #pragma unroll
            for (int n = 0; n < NREP; ++n)
                b[n] = *(const bf16x8*)(Bs + (wc * (BN / 2) + n * 16 + (lane & 15)) * LDT
                                        + ks * 32 + (lane >> 4) * 8);
            #pragma unroll
            for (int m = 0; m < MREP; ++m)
                #pragma unroll
                for (int n = 0; n < NREP; ++n)
                    acc[m][n] = __builtin_amdgcn_mfma_f32_16x16x32_bf16(a[m], b[n], acc[m][n], 0, 0, 0);
        }
        __syncthreads();
    }
    // C/D layout (m89): col = lane&15, row = (lane>>4)*4 + reg
    #pragma unroll
    for (int m = 0; m < MREP; ++m) {
        #pragma unroll
        for (int n = 0; n < NREP; ++n) {
            #pragma unroll
            for (int r = 0; r < 4; ++r) {
                int grow = m0 + wr * (BM / 2) + m * 16 + (lane >> 4) * 4 + r;
                int gcol = n0 + wc * (BN / 2) + n * 16 + (lane & 15);
                if (grow < M) C[(size_t)grow * N + gcol] = f2bf(acc[m][n][r]);
            }
        }
    }
}

// ---------- FUSED layer-1 aggregation + layer-2 GEMM ----------
// 625 blocks x 512 threads (8 waves); 32 nodes/block (20000 = 625*32, no tail).
// Phase 1: wave w aggregates nodes nbase+w*4..+3 (ILP-4 gather), h1 -> LDS (bf16).
// Phase 2: 8 waves compute the 32x64 support2 tile (8 MFMA each, K=256),
//          B-fragments streamed from L2-hot w2t (32 KB). h1 never touches HBM.
#define H1LD 264    // 256 + 8 shorts: a-frag reads 2-way bank alias (free, m136)
__global__ __launch_bounds__(512) void k_agg1_gemm2(
    const short* __restrict__ support, const int* __restrict__ row_ptr,
    const int2* __restrict__ epack, const float* __restrict__ b1,
    const short* __restrict__ w2t, short* __restrict__ support2)
{
    __shared__ short h1s[32 * H1LD];   // 16.9 KB
    int tid = threadIdx.x, lane = tid & 63, w = tid >> 6;
    int nbase = blockIdx.x * 32;

    // ---- phase 1: aggregation, 4 nodes per wave ----
    #pragma unroll
    for (int q = 0; q < 4; ++q) {
        int nl = w * 4 + q;
        int node = nbase + nl;
        int e0 = row_ptr[node], e1 = row_ptr[node + 1];
        float a0[4] = {}, a1[4] = {}, a2[4] = {}, a3[4] = {};
        int e = e0;
        for (; e + 4 <= e1; e += 4) {
            int2 m0 = epack[e + 0], m1 = epack[e + 1], m2 = epack[e + 2], m3 = epack[e + 3];
            ushort4 v0 = *(const ushort4*)(support + (size_t)m0.x * NHID + lane * 4);
            ushort4 v1 = *(const ushort4*)(support + (size_t)m1.x * NHID + lane * 4);
            ushort4 v2 = *(const ushort4*)(support + (size_t)m2.x * NHID + lane * 4);
            ushort4 v3 = *(const ushort4*)(support + (size_t)m3.x * NHID + lane * 4);
            float w0 = __builtin_bit_cast(float, m0.y), w1 = __builtin_bit_cast(float, m1.y);
            float w2 = __builtin_bit_cast(float, m2.y), w3 = __builtin_bit_cast(float, m3.y);
            a0[0] = fmaf(w0, bf2f(v0.x), a0[0]); a0[1] = fmaf(w0, bf2f(v0.y), a0[1]);
            a0[2] = fmaf(w0, bf2f(v0.z), a0[2]); a0[3] = fmaf(w0, bf2f(v0.w), a0[3]);
            a1[0] = fmaf(w1, bf2f(v1.x), a1[0]); a1[1] = fmaf(w1, bf2f(v1.y), a1[1]);
            a1[2] = fmaf(w1, bf2f(v1.z), a1[2]); a1[3] = fmaf(w1, bf2f(v1.w), a1[3]);
            a2[0] = fmaf(w2, bf2f(v2.x), a2[0]); a2[1] = fmaf(w2, bf2f(v2.y), a2[1]);
            a2[2] = fmaf(w2, bf2f(v2.z), a2[2]); a2[3] = fmaf(w2, bf2f(v2.w), a2[3]);
            a3[0] = fmaf(w3, bf2f(v3.x), a3[0]); a3[1] = fmaf(w3, bf2f(v3.y), a3[1]);
            a3[2] = fmaf(w3, bf2f(v3.z), a3[2]); a3[3] = fmaf(w3, bf2f(v3.w), a3[3]);
        }
        for (; e < e1; ++e) {
            int2 m = epack[e];
            float wgt = __builtin_bit_cast(float, m.y);
            ushort4 v = *(const ushort4*)(support + (size_t)m.x * NHID + lane * 4);
            a0[0] = fmaf(wgt, bf2f(v.x), a0[0]); a0[1] = fmaf(wgt, bf2f(v.y), a0[1]);
            a0[2] = fmaf(wgt, bf2f(v.z), a0[2]); a0[3] = fmaf(wgt, bf2f(v.w), a0[3]);
        }
        ushort4 o;
        o.x = (unsigned short)f2bf(selu_f(a0[0] + a1[0] + a2[0] + a3[0] + b1[lane * 4 + 0]));
        o.y = (unsigned short)f2bf(selu_f(a0[1] + a1[1] + a2[1] + a3[1] + b1[lane * 4 + 1]));
        o.z = (unsigned short)f2bf(selu_f(a0[2] + a1[2] + a2[2] + a3[2] + b1[lane * 4 + 2]));
        o.w = (unsigned short)f2bf(selu_f(a0[3] + a1[3] + a2[3] + a3[3] + b1[lane * 4 + 3]));
        *(ushort4*)(h1s + nl * H1LD + lane * 4) = o;
    }
    __syncthreads();

    // ---- phase 2: 32x64 GEMM vs w2t (K=256); wave w -> 16x16 tile (tr=w>>2, tc=w&3) ----
    int tr = w >> 2, tc = w & 3;
    f32x4 acc = {};
    #pragma unroll
    for (int kk = 0; kk < NHID / 32; ++kk) {
        bf16x8 a = *(const bf16x8*)(h1s + (tr * 16 + (lane & 15)) * H1LD
                                    + kk * 32 + (lane >> 4) * 8);
        bf16x8 b = *(const bf16x8*)(w2t + (size_t)(tc * 16 + (lane & 15)) * NHID
                                    + kk * 32 + (lane >> 4) * 8);
        acc = __builtin_amdgcn_mfma_f32_16x16x32_bf16(a, b, acc, 0, 0, 0);
    }
    #pragma unroll
    for (int r = 0; r < 4; ++r) {
        int grow = nbase + tr * 16 + (lane >> 4) * 4 + r;
        int gcol = tc * 16 + (lane & 15);
        support2[(size_t)grow * NCLASS + gcol] = f2bf(acc[r]);
    }
}

// ---------- layer-2 aggregation: 2 nodes/wave, ILP-4, block-level partials ----------
#define AGG2_BLOCKS (N_NODES / 8)    // 2500 blocks, 8 nodes/block
__global__ __launch_bounds__(256) void k_agg2(const short* __restrict__ support2,
                                              const int* __restrict__ row_ptr,
                                              const int2* __restrict__ epack,
                                              const float* __restrict__ b2,
                                              float* __restrict__ partial) {
    __shared__ float bsum[4][64];
    int tid = threadIdx.x, lane = tid & 63, wave = tid >> 6;
    float bias = b2[lane];
    float local = 0.f;
    #pragma unroll
    for (int q = 0; q < 2; ++q) {
        int node = blockIdx.x * 8 + wave * 2 + q;
        int e0 = row_ptr[node], e1 = row_ptr[node + 1];
        float s0 = 0.f, s1 = 0.f, s2 = 0.f, s3 = 0.f;
        int e = e0;
        for (; e + 4 <= e1; e += 4) {
            int2 m0 = epack[e + 0], m1 = epack[e + 1], m2 = epack[e + 2], m3 = epack[e + 3];
            float v0 = bf2f((unsigned short)support2[(size_t)m0.x * NCLASS + lane]);
            float v1 = bf2f((unsigned short)support2[(size_t)m1.x * NCLASS + lane]);
            float v2 = bf2f((unsigned short)support2[(size_t)m2.x * NCLASS + lane]);
            float v3 = bf2f((unsigned short)support2[(size_t)m3.x * NCLASS + lane]);
            s0 = fmaf(__builtin_bit_cast(float, m0.y), v0, s0);
            s1 = fmaf(__builtin_bit_cast(float, m1.y), v1, s1);
            s2 = fmaf(__builtin_bit_cast(float, m2.y), v2, s2);
            s3 = fmaf(__builtin_bit_cast(float, m3.y), v3, s3);
        }
        for (; e < e1; ++e) {
            int2 m = epack[e];
            s0 = fmaf(__builtin_bit_cast(float, m.y),
                      bf2f((unsigned short)support2[(size_t)m.x * NCLASS + lane]), s0);
        }
        local += selu_f(s0 + s1 + s2 + s3 + bias);
    }
    bsum[wave][lane] = local;
    __syncthreads();
    if (tid < 64)
        partial[(size_t)blockIdx.x * 64 + tid] =
            bsum[0][tid] + bsum[1][tid] + bsum[2][tid] + bsum[3][tid];
}

// ---------- reduce stage 1: 50 blocks x 50 rows -> stage2[50][64] ----------
#define RED_BLOCKS 50
#define RED_ROWS (AGG2_BLOCKS / RED_BLOCKS)   // 50
__global__ __launch_bounds__(256) void k_reduce1(const float* __restrict__ partial,
                                                 float* __restrict__ stage2) {
    __shared__ float red[4][64];
    int tid = threadIdx.x, lane = tid & 63, sl = tid >> 6;
    int r0 = blockIdx.x * RED_ROWS;
    float s = 0.f;
    for (int i = sl; i < RED_ROWS; i += 4)        // coalesced 256B rows, indep loads
        s += partial[(size_t)(r0 + i) * 64 + lane];
    red[sl][lane] = s;
    __syncthreads();
    if (tid < 64)
        stage2[(size_t)blockIdx.x * 64 + tid] =
            red[0][tid] + red[1][tid] + red[2][tid] + red[3][tid];
}

// ---------- final: sum 50 stage2 rows -> mean -> selu -> log_softmax (1 wave) ----------
__global__ void k_final(const float* __restrict__ stage2, float* __restrict__ out) {
    int lane = threadIdx.x;   // 64 threads
    float tot = 0.f;
    #pragma unroll
    for (int i = 0; i < RED_BLOCKS; ++i)          // independent loads, one latency
        tot += stage2[(size_t)i * 64 + lane];
    float v = selu_f(tot * (1.0f / N_NODES));
    float m = v;
    #pragma unroll
    for (int off = 32; off >= 1; off >>= 1) m = fmaxf(m, __shfl_xor(m, off));
    float ex = expf(v - m);
    float ssum = ex;
    #pragma unroll
    for (int off = 32; off >= 1; off >>= 1) ssum += __shfl_xor(ssum, off);
    out[lane] = v - m - logf(ssum);
}

extern "C" void kernel_launch(void* const* d_in, const int* in_sizes, int n_in,
                              void* d_out, int out_size, void* d_ws, size_t ws_size,
                              hipStream_t stream) {
    const float* x  = (const float*)d_in[0];
    const int* ei   = (const int*)d_in[1];
    const float* ew = (const float*)d_in[2];
    const float* W1 = (const float*)d_in[3];
    const float* b1 = (const float*)d_in[4];
    const float* W2 = (const float*)d_in[5];
    const float* b2 = (const float*)d_in[6];
    float* out = (float*)d_out;
    const int* e_row = ei;
    const int* e_col = ei + N_EDGES;

    char* p = (char*)d_ws;
    short* w1t      = (short*)p;  p += (size_t)NHID * NFEAT * 2;        //  0.26 MB
    short* w2t      = (short*)p;  p += (size_t)NCLASS * NHID * 2;       //  0.03 MB
    short* support1 = (short*)p;  p += (size_t)N_NODES * NHID * 2;      // 10.24 MB
    int* counts     = (int*)p;    p += (size_t)N_NODES * 4;
    int* row_ptr    = (int*)p;    p += (size_t)(N_NODES + 1) * 4;
    int* write_ptr  = (int*)p;    p += (size_t)N_NODES * 4;
    int2* epack     = (int2*)p;   p += (size_t)N_EDGES * 8;             //  2.56 MB
    float* partial  = (float*)p;  p += (size_t)AGG2_BLOCKS * 64 * 4;    //  0.64 MB
    float* stage2   = (float*)p;  p += (size_t)RED_BLOCKS * 64 * 4;     //  0.01 MB
    short* support2 = (short*)p;  p += (size_t)N_NODES * NCLASS * 2;    //  2.56 MB

    hipMemsetAsync(counts, 0, (size_t)N_NODES * 4, stream);

    // CSR count + coalesced weight transpose-casts (disjoint block ranges)
    k_count_cast<<<EDGE_BLOCKS + W1_TILES + W2_TILES, 256, 0, stream>>>(
        e_row, counts, W1, W2, w1t, w2t);
    k_scan<<<1, 1024, 0, stream>>>(counts, row_ptr, write_ptr);
    k_scatter<<<(N_EDGES + 255) / 256, 256, 0, stream>>>(e_row, e_col, ew, write_ptr, epack);

    // layer 1 GEMM: 64x256 tile, single column pass -> x fp32 read exactly once (82 MB)
    k_gemm_bf16<64, 256, 64, 2, 8, true>
        <<<dim3((N_NODES + 63) / 64, NHID / 256), 256, 0, stream>>>(
            x, w1t, support1, N_NODES, NHID, NFEAT);

    // fused agg1 + gemm2: h1 lives only in LDS (saves 20 MB HBM + 1 launch)
    k_agg1_gemm2<<<N_NODES / 32, 512, 0, stream>>>(
        support1, row_ptr, epack, b1, w2t, support2);

    k_agg2<<<AGG2_BLOCKS, 256, 0, stream>>>(support2, row_ptr, epack, b2, partial);
    k_reduce1<<<RED_BLOCKS, 256, 0, stream>>>(partial, stage2);
    k_final<<<1, 64, 0, stream>>>(stage2, out);
}

// Round 15
// 198.011 us; speedup vs baseline: 1.1634x; 1.0995x over previous
//
#include <hip/hip_runtime.h>
#include <math.h>

#define N_NODES 20000
#define N_EDGES 320000
#define NFEAT 512
#define NHID 256
#define NCLASS 64

typedef __attribute__((ext_vector_type(8))) short bf16x8;
typedef __attribute__((ext_vector_type(4))) float f32x4;

__device__ __forceinline__ float selu_f(float x) {
    const float alpha = 1.6732632423543772f;
    const float scale = 1.0507009873554805f;
    return x > 0.f ? scale * x : scale * alpha * (expf(x) - 1.f);
}

__device__ __forceinline__ short f2bf(float f) {
    unsigned u = __builtin_bit_cast(unsigned, f);
    unsigned r = (u + 0x7FFFu + ((u >> 16) & 1u)) >> 16;   // RNE
    return (short)r;
}

__device__ __forceinline__ float bf2f(unsigned short b) {
    unsigned u = ((unsigned)b) << 16;
    return __builtin_bit_cast(float, u);
}

// ---------- fused: edge count+rank + coalesced 32x32 LDS-tiled weight transpose ----------
// rank[e] = this edge's arrival order within its node -> scatter needs no atomics.
#define EDGE_BLOCKS ((N_EDGES + 255) / 256)          // 1250
#define W1_TILES ((NFEAT / 32) * (NHID / 32))        // 16 x 8 = 128
#define W2_TILES ((NHID / 32) * (NCLASS / 32))       // 8 x 2 = 16
__global__ __launch_bounds__(256) void k_count_cast(
    const int* __restrict__ row, int* __restrict__ counts, int* __restrict__ rank,
    const float* __restrict__ W1, const float* __restrict__ W2,
    short* __restrict__ w1t, short* __restrict__ w2t)
{
    __shared__ float tile[32][33];
    int b = blockIdx.x, tid = threadIdx.x;
    if (b < EDGE_BLOCKS) {
        int e = b * 256 + tid;
        if (e < N_EDGES) rank[e] = atomicAdd(&counts[row[e]], 1);
        return;
    }
    int t = b - EDGE_BLOCKS;
    const float* W; short* Wt; int K, N, tk, tn;
    if (t < W1_TILES) { W = W1; Wt = w1t; K = NFEAT; N = NHID; tk = t & 15; tn = t >> 4; }
    else { t -= W1_TILES; W = W2; Wt = w2t; K = NHID; N = NCLASS; tk = t & 7; tn = t >> 3; }
    int c = tid & 31, r0 = tid >> 5;                 // 8 rows per pass
    int k0 = tk * 32, n0 = tn * 32;
    #pragma unroll
    for (int i = 0; i < 4; ++i) {
        int r = r0 + i * 8;
        tile[r][c] = W[(size_t)(k0 + r) * N + n0 + c];   // coalesced read
    }
    __syncthreads();
    #pragma unroll
    for (int i = 0; i < 4; ++i) {
        int r = r0 + i * 8;
        Wt[(size_t)(n0 + r) * K + k0 + c] = f2bf(tile[c][r]);  // coalesced write
    }
}

// single-pass scan: 1024 threads x 20 contiguous elems each, 2 barriers total
__global__ __launch_bounds__(1024) void k_scan(const int* __restrict__ counts,
                                               int* __restrict__ row_ptr) {
    __shared__ int wsum[16];
    int tid = threadIdx.x, lane = tid & 63, wave = tid >> 6;
    int base = tid * 20;
    int v[20];
    int s = 0;
    #pragma unroll
    for (int j = 0; j < 20; ++j) {
        int i = base + j;
        int c = (i < N_NODES) ? counts[i] : 0;
        v[j] = s;                 // exclusive prefix within thread
        s += c;
    }
    int ws = s;                    // inclusive wave scan of thread totals
    #pragma unroll
    for (int d = 1; d < 64; d <<= 1) {
        int t = __shfl_up(ws, d);
        if (lane >= d) ws += t;
    }
    if (lane == 63) wsum[wave] = ws;
    __syncthreads();
    if (wave == 0) {
        int t = (lane < 16) ? wsum[lane] : 0;
        #pragma unroll
        for (int d = 1; d < 16; d <<= 1) {
            int u = __shfl_up(t, d);
            if (lane >= d) t += u;
        }
        if (lane < 16) wsum[lane] = t;   // inclusive over waves
    }
    __syncthreads();
    int off = (wave ? wsum[wave - 1] : 0) + (ws - s);
    #pragma unroll
    for (int j = 0; j < 20; ++j) {
        int i = base + j;
        if (i < N_NODES) row_ptr[i] = off + v[j];
    }
    if (tid == 0) row_ptr[N_NODES] = wsum[15];
}

// atomic-free scatter: pos = row_ptr[row] + rank  (rank from the count pass)
__global__ void k_scatter(const int* __restrict__ row, const int* __restrict__ col,
                          const float* __restrict__ w, const int* __restrict__ row_ptr,
                          const int* __restrict__ rank, int2* __restrict__ epack) {
    int e = blockIdx.x * blockDim.x + threadIdx.x;
    if (e < N_EDGES) {
        int pos = row_ptr[row[e]] + rank[e];
        epack[pos] = make_int2(col[e], __builtin_bit_cast(int, w[e]));
    }
}

// ---------- bf16 MFMA GEMM: C[M,N] = A[M,K] @ Bt[N,K]^T; A fp32 (cast fused) or bf16 ----------
template<int BM, int BN, int BK, int MREP, int NREP, bool AFP32>
__global__ __launch_bounds__(256) void k_gemm_bf16(
    const void* __restrict__ Av, const short* __restrict__ Bt,
    short* __restrict__ C, int M, int N, int K)
{
    constexpr int LDT = BK + 8;   // +16B pad: frag reads 2-way bank alias (free, m136)
    __shared__ short As[BM * LDT];
    __shared__ short Bs[BN * LDT];
    const int tid = threadIdx.x;
    const int lane = tid & 63;
    const int w = tid >> 6;
    const int wr = w >> 1, wc = w & 1;
    const int m0 = blockIdx.x * BM, n0 = blockIdx.y * BN;
    constexpr int SEGS = BK / 8;
    constexpr int A_ITER = BM * SEGS / 256;
    constexpr int B_ITER = BN * SEGS / 256;

    f32x4 acc[MREP][NREP] = {};

    for (int kt = 0; kt < K; kt += BK) {
        #pragma unroll
        for (int it = 0; it < A_ITER; ++it) {
            int idx = tid + it * 256;
            int r = idx / SEGS, seg = idx % SEGS;
            int gr = m0 + r; if (gr >= M) gr = M - 1;   // clamp: dup load, store predicated
            bf16x8 o;
            if constexpr (AFP32) {
                const float* ap = (const float*)Av + (size_t)gr * K + kt + seg * 8;
                float4 p0 = *(const float4*)ap, p1 = *(const float4*)(ap + 4);
                o[0] = f2bf(p0.x); o[1] = f2bf(p0.y); o[2] = f2bf(p0.z); o[3] = f2bf(p0.w);
                o[4] = f2bf(p1.x); o[5] = f2bf(p1.y); o[6] = f2bf(p1.z); o[7] = f2bf(p1.w);
            } else {
                o = *(const bf16x8*)((const short*)Av + (size_t)gr * K + kt + seg * 8);
            }
            *(bf16x8*)(As + r * LDT + seg * 8) = o;
        }
        #pragma unroll
        for (int it = 0; it < B_ITER; ++it) {
            int idx = tid + it * 256;
            int r = idx / SEGS, seg = idx % SEGS;
            *(bf16x8*)(Bs + r * LDT + seg * 8) =
                *(const bf16x8*)(Bt + (size_t)(n0 + r) * K + kt + seg * 8);
        }
        __syncthreads();
        #pragma unroll
        for (int ks = 0; ks < BK / 32; ++ks) {
            bf16x8 a[MREP], b[NREP];
            #pragma unroll
            for (int m = 0; m < MREP; ++m)
                a[m] = *(const bf16x8*)(As + (wr * (BM / 2) + m * 16 + (lane & 15)) * LDT
                                        + ks * 32 + (lane >> 4) * 8);
            #pragma unroll
            for (int n = 0; n < NREP; ++n)
                b[n] = *(const bf16x8*)(Bs + (wc * (BN / 2) + n * 16 + (lane & 15)) * LDT
                                        + ks * 32 + (lane >> 4) * 8);
            #pragma unroll
            for (int m = 0; m < MREP; ++m)
                #pragma unroll
                for (int n = 0; n < NREP; ++n)
                    acc[m][n] = __builtin_amdgcn_mfma_f32_16x16x32_bf16(a[m], b[n], acc[m][n], 0, 0, 0);
        }
        __syncthreads();
    }
    // C/D layout (m89): col = lane&15, row = (lane>>4)*4 + reg
    #pragma unroll
    for (int m = 0; m < MREP; ++m) {
        #pragma unroll
        for (int n = 0; n < NREP; ++n) {
            #pragma unroll
            for (int r = 0; r < 4; ++r) {
                int grow = m0 + wr * (BM / 2) + m * 16 + (lane >> 4) * 4 + r;
                int gcol = n0 + wc * (BN / 2) + n * 16 + (lane & 15);
                if (grow < M) C[(size_t)grow * N + gcol] = f2bf(acc[m][n][r]);
            }
        }
    }
}

// ---------- FUSED layer-1 aggregation + layer-2 GEMM ----------
// 625 blocks x 512 threads (8 waves); 32 nodes/block (20000 = 625*32, no tail).
#define H1LD 264    // 256 + 8 shorts: a-frag reads 2-way bank alias (free, m136)
__global__ __launch_bounds__(512) void k_agg1_gemm2(
    const short* __restrict__ support, const int* __restrict__ row_ptr,
    const int2* __restrict__ epack, const float* __restrict__ b1,
    const short* __restrict__ w2t, short* __restrict__ support2)
{
    __shared__ short h1s[32 * H1LD];   // 16.9 KB
    int tid = threadIdx.x, lane = tid & 63, w = tid >> 6;
    int nbase = blockIdx.x * 32;

    // ---- phase 1: aggregation, 4 nodes per wave ----
    #pragma unroll
    for (int q = 0; q < 4; ++q) {
        int nl = w * 4 + q;
        int node = nbase + nl;
        int e0 = row_ptr[node], e1 = row_ptr[node + 1];
        float a0[4] = {}, a1[4] = {}, a2[4] = {}, a3[4] = {};
        int e = e0;
        for (; e + 4 <= e1; e += 4) {
            int2 m0 = epack[e + 0], m1 = epack[e + 1], m2 = epack[e + 2], m3 = epack[e + 3];
            ushort4 v0 = *(const ushort4*)(support + (size_t)m0.x * NHID + lane * 4);
            ushort4 v1 = *(const ushort4*)(support + (size_t)m1.x * NHID + lane * 4);
            ushort4 v2 = *(const ushort4*)(support + (size_t)m2.x * NHID + lane * 4);
            ushort4 v3 = *(const ushort4*)(support + (size_t)m3.x * NHID + lane * 4);
            float w0 = __builtin_bit_cast(float, m0.y), w1 = __builtin_bit_cast(float, m1.y);
            float w2 = __builtin_bit_cast(float, m2.y), w3 = __builtin_bit_cast(float, m3.y);
            a0[0] = fmaf(w0, bf2f(v0.x), a0[0]); a0[1] = fmaf(w0, bf2f(v0.y), a0[1]);
            a0[2] = fmaf(w0, bf2f(v0.z), a0[2]); a0[3] = fmaf(w0, bf2f(v0.w), a0[3]);
            a1[0] = fmaf(w1, bf2f(v1.x), a1[0]); a1[1] = fmaf(w1, bf2f(v1.y), a1[1]);
            a1[2] = fmaf(w1, bf2f(v1.z), a1[2]); a1[3] = fmaf(w1, bf2f(v1.w), a1[3]);
            a2[0] = fmaf(w2, bf2f(v2.x), a2[0]); a2[1] = fmaf(w2, bf2f(v2.y), a2[1]);
            a2[2] = fmaf(w2, bf2f(v2.z), a2[2]); a2[3] = fmaf(w2, bf2f(v2.w), a2[3]);
            a3[0] = fmaf(w3, bf2f(v3.x), a3[0]); a3[1] = fmaf(w3, bf2f(v3.y), a3[1]);
            a3[2] = fmaf(w3, bf2f(v3.z), a3[2]); a3[3] = fmaf(w3, bf2f(v3.w), a3[3]);
        }
        for (; e < e1; ++e) {
            int2 m = epack[e];
            float wgt = __builtin_bit_cast(float, m.y);
            ushort4 v = *(const ushort4*)(support + (size_t)m.x * NHID + lane * 4);
            a0[0] = fmaf(wgt, bf2f(v.x), a0[0]); a0[1] = fmaf(wgt, bf2f(v.y), a0[1]);
            a0[2] = fmaf(wgt, bf2f(v.z), a0[2]); a0[3] = fmaf(wgt, bf2f(v.w), a0[3]);
        }
        ushort4 o;
        o.x = (unsigned short)f2bf(selu_f(a0[0] + a1[0] + a2[0] + a3[0] + b1[lane * 4 + 0]));
        o.y = (unsigned short)f2bf(selu_f(a0[1] + a1[1] + a2[1] + a3[1] + b1[lane * 4 + 1]));
        o.z = (unsigned short)f2bf(selu_f(a0[2] + a1[2] + a2[2] + a3[2] + b1[lane * 4 + 2]));
        o.w = (unsigned short)f2bf(selu_f(a0[3] + a1[3] + a2[3] + a3[3] + b1[lane * 4 + 3]));
        *(ushort4*)(h1s + nl * H1LD + lane * 4) = o;
    }
    __syncthreads();

    // ---- phase 2: 32x64 GEMM vs w2t (K=256); wave w -> 16x16 tile (tr=w>>2, tc=w&3) ----
    int tr = w >> 2, tc = w & 3;
    f32x4 acc = {};
    #pragma unroll
    for (int kk = 0; kk < NHID / 32; ++kk) {
        bf16x8 a = *(const bf16x8*)(h1s + (tr * 16 + (lane & 15)) * H1LD
                                    + kk * 32 + (lane >> 4) * 8);
        bf16x8 b = *(const bf16x8*)(w2t + (size_t)(tc * 16 + (lane & 15)) * NHID
                                    + kk * 32 + (lane >> 4) * 8);
        acc = __builtin_amdgcn_mfma_f32_16x16x32_bf16(a, b, acc, 0, 0, 0);
    }
    #pragma unroll
    for (int r = 0; r < 4; ++r) {
        int grow = nbase + tr * 16 + (lane >> 4) * 4 + r;
        int gcol = tc * 16 + (lane & 15);
        support2[(size_t)grow * NCLASS + gcol] = f2bf(acc[r]);
    }
}

// ---------- layer-2 aggregation: 2 nodes/wave, ILP-4, block-level partials ----------
#define AGG2_BLOCKS (N_NODES / 8)    // 2500 blocks, 8 nodes/block
__global__ __launch_bounds__(256) void k_agg2(const short* __restrict__ support2,
                                              const int* __restrict__ row_ptr,
                                              const int2* __restrict__ epack,
                                              const float* __restrict__ b2,
                                              float* __restrict__ partial) {
    __shared__ float bsum[4][64];
    int tid = threadIdx.x, lane = tid & 63, wave = tid >> 6;
    float bias = b2[lane];
    float local = 0.f;
    #pragma unroll
    for (int q = 0; q < 2; ++q) {
        int node = blockIdx.x * 8 + wave * 2 + q;
        int e0 = row_ptr[node], e1 = row_ptr[node + 1];
        float s0 = 0.f, s1 = 0.f, s2 = 0.f, s3 = 0.f;
        int e = e0;
        for (; e + 4 <= e1; e += 4) {
            int2 m0 = epack[e + 0], m1 = epack[e + 1], m2 = epack[e + 2], m3 = epack[e + 3];
            float v0 = bf2f((unsigned short)support2[(size_t)m0.x * NCLASS + lane]);
            float v1 = bf2f((unsigned short)support2[(size_t)m1.x * NCLASS + lane]);
            float v2 = bf2f((unsigned short)support2[(size_t)m2.x * NCLASS + lane]);
            float v3 = bf2f((unsigned short)support2[(size_t)m3.x * NCLASS + lane]);
            s0 = fmaf(__builtin_bit_cast(float, m0.y), v0, s0);
            s1 = fmaf(__builtin_bit_cast(float, m1.y), v1, s1);
            s2 = fmaf(__builtin_bit_cast(float, m2.y), v2, s2);
            s3 = fmaf(__builtin_bit_cast(float, m3.y), v3, s3);
        }
        for (; e < e1; ++e) {
            int2 m = epack[e];
            s0 = fmaf(__builtin_bit_cast(float, m.y),
                      bf2f((unsigned short)support2[(size_t)m.x * NCLASS + lane]), s0);
        }
        local += selu_f(s0 + s1 + s2 + s3 + bias);
    }
    bsum[wave][lane] = local;
    __syncthreads();
    if (tid < 64)
        partial[(size_t)blockIdx.x * 64 + tid] =
            bsum[0][tid] + bsum[1][tid] + bsum[2][tid] + bsum[3][tid];
}

// ---------- reduce stage 1: 50 blocks x 50 rows -> stage2[50][64] ----------
#define RED_BLOCKS 50
#define RED_ROWS (AGG2_BLOCKS / RED_BLOCKS)   // 50
__global__ __launch_bounds__(256) void k_reduce1(const float* __restrict__ partial,
                                                 float* __restrict__ stage2) {
    __shared__ float red[4][64];
    int tid = threadIdx.x, lane = tid & 63, sl = tid >> 6;
    int r0 = blockIdx.x * RED_ROWS;
    float s = 0.f;
    for (int i = sl; i < RED_ROWS; i += 4)        // coalesced 256B rows, indep loads
        s += partial[(size_t)(r0 + i) * 64 + lane];
    red[sl][lane] = s;
    __syncthreads();
    if (tid < 64)
        stage2[(size_t)blockIdx.x * 64 + tid] =
            red[0][tid] + red[1][tid] + red[2][tid] + red[3][tid];
}

// ---------- final: sum 50 stage2 rows -> mean -> selu -> log_softmax (1 wave) ----------
__global__ void k_final(const float* __restrict__ stage2, float* __restrict__ out) {
    int lane = threadIdx.x;   // 64 threads
    float tot = 0.f;
    #pragma unroll
    for (int i = 0; i < RED_BLOCKS; ++i)          // independent loads, one latency
        tot += stage2[(size_t)i * 64 + lane];
    float v = selu_f(tot * (1.0f / N_NODES));
    float m = v;
    #pragma unroll
    for (int off = 32; off >= 1; off >>= 1) m = fmaxf(m, __shfl_xor(m, off));
    float ex = expf(v - m);
    float ssum = ex;
    #pragma unroll
    for (int off = 32; off >= 1; off >>= 1) ssum += __shfl_xor(ssum, off);
    out[lane] = v - m - logf(ssum);
}

extern "C" void kernel_launch(void* const* d_in, const int* in_sizes, int n_in,
                              void* d_out, int out_size, void* d_ws, size_t ws_size,
                              hipStream_t stream) {
    const float* x  = (const float*)d_in[0];
    const int* ei   = (const int*)d_in[1];
    const float* ew = (const float*)d_in[2];
    const float* W1 = (const float*)d_in[3];
    const float* b1 = (const float*)d_in[4];
    const float* W2 = (const float*)d_in[5];
    const float* b2 = (const float*)d_in[6];
    float* out = (float*)d_out;
    const int* e_row = ei;
    const int* e_col = ei + N_EDGES;

    char* p = (char*)d_ws;
    short* w1t      = (short*)p;  p += (size_t)NHID * NFEAT * 2;        //  0.26 MB
    short* w2t      = (short*)p;  p += (size_t)NCLASS * NHID * 2;       //  0.03 MB
    short* support1 = (short*)p;  p += (size_t)N_NODES * NHID * 2;      // 10.24 MB
    int* counts     = (int*)p;    p += (size_t)N_NODES * 4;
    int* row_ptr    = (int*)p;    p += (size_t)(N_NODES + 1) * 4;
    int* rank       = (int*)p;    p += (size_t)N_EDGES * 4;             //  1.28 MB
    int2* epack     = (int2*)p;   p += (size_t)N_EDGES * 8;             //  2.56 MB
    float* partial  = (float*)p;  p += (size_t)AGG2_BLOCKS * 64 * 4;    //  0.64 MB
    float* stage2   = (float*)p;  p += (size_t)RED_BLOCKS * 64 * 4;     //  0.01 MB
    short* support2 = (short*)p;  p += (size_t)N_NODES * NCLASS * 2;    //  2.56 MB

    hipMemsetAsync(counts, 0, (size_t)N_NODES * 4, stream);

    // CSR count (records per-edge rank) + coalesced weight transpose-casts
    k_count_cast<<<EDGE_BLOCKS + W1_TILES + W2_TILES, 256, 0, stream>>>(
        e_row, counts, rank, W1, W2, w1t, w2t);
    k_scan<<<1, 1024, 0, stream>>>(counts, row_ptr);
    k_scatter<<<(N_EDGES + 255) / 256, 256, 0, stream>>>(
        e_row, e_col, ew, row_ptr, rank, epack);

    // layer 1 GEMM: 64x256 tile, single column pass -> x fp32 read exactly once
    k_gemm_bf16<64, 256, 64, 2, 8, true>
        <<<dim3((N_NODES + 63) / 64, NHID / 256), 256, 0, stream>>>(
            x, w1t, support1, N_NODES, NHID, NFEAT);

    // fused agg1 + gemm2: h1 lives only in LDS
    k_agg1_gemm2<<<N_NODES / 32, 512, 0, stream>>>(
        support1, row_ptr, epack, b1, w2t, support2);

    k_agg2<<<AGG2_BLOCKS, 256, 0, stream>>>(support2, row_ptr, epack, b2, partial);
    k_reduce1<<<RED_BLOCKS, 256, 0, stream>>>(partial, stage2);
    k_final<<<1, 64, 0, stream>>>(stage2, out);
}